// Round 4
// baseline (312.783 us; speedup 1.0000x reference)
//
#include <hip/hip_runtime.h>
#include <math.h>

#define SELU_SCALE 1.0507009873554804934193349852946f
#define SELU_ALPHA 1.6732632423543772848170429916717f

typedef short bf16x8 __attribute__((ext_vector_type(8)));
typedef float f32x4 __attribute__((ext_vector_type(4)));

__device__ __forceinline__ float selu_f(float x) {
    return SELU_SCALE * (x > 0.f ? x : SELU_ALPHA * expm1f(x));
}

__device__ __forceinline__ unsigned short f2bf(float f) {
    unsigned int u = __float_as_uint(f);
    u += 0x7FFF + ((u >> 16) & 1);  // round-to-nearest-even
    return (unsigned short)(u >> 16);
}
__device__ __forceinline__ float bflo(unsigned int u) { return __uint_as_float(u << 16); }
__device__ __forceinline__ float bfhi(unsigned int u) { return __uint_as_float(u & 0xFFFF0000u); }

__device__ __forceinline__ void acc8(float* a, uint4 v) {
    a[0] += bflo(v.x); a[1] += bfhi(v.x);
    a[2] += bflo(v.y); a[3] += bfhi(v.y);
    a[4] += bflo(v.z); a[5] += bfhi(v.z);
    a[6] += bflo(v.w); a[7] += bfhi(v.w);
}

// ---------------------------------------------------------------------------
// K1: local covariance (window 25, divisor 23) + [x,cov] @ w_e1 + b_e1, selu,
// prescaled by dinv[p], stored bf16.  LDS-staged x tile, single-pass moments.
// ---------------------------------------------------------------------------
__global__ __launch_bounds__(256) void cov_enc_kernel(
    const float* __restrict__ x, const float* __restrict__ w_e1,
    const float* __restrict__ b_e1, const float* __restrict__ dinv,
    unsigned short* __restrict__ hs1, int BN) {
    __shared__ float Wl[12 * 64];
    __shared__ float Bl[64];
    __shared__ float xs[280 * 3];
    int t = threadIdx.x;
    for (int i = t; i < 768; i += 256) Wl[i] = w_e1[i];
    if (t < 64) Bl[t] = b_e1[t];
    int p0 = blockIdx.x * 256;
    int n0 = p0 & 4095;
    const float* xb = x + (size_t)(p0 - n0) * 3;  // batch base (256 | 4096)
    for (int idx = t; idx < 840; idx += 256) {
        int slot = idx / 3, d = idx - slot * 3;
        int g = n0 - 12 + slot;
        g = g < 0 ? 0 : (g > 4095 ? 4095 : g);
        xs[idx] = xb[g * 3 + d];
    }
    __syncthreads();
    int p = p0 + t;
    int n = n0 + t;
    int lo = n - 12 < 0 ? 0 : n - 12;
    int hi = n + 12 > 4095 ? 4095 : n + 12;
    int slo = lo - n0 + 12, shi = hi - n0 + 12;
    float sx = 0.f, sy = 0.f, sz = 0.f;
    float sxx = 0.f, sxy = 0.f, sxz = 0.f, syy = 0.f, syz = 0.f, szz = 0.f;
    for (int s = slo; s <= shi; s++) {
        float xv = xs[s * 3 + 0], yv = xs[s * 3 + 1], zv = xs[s * 3 + 2];
        sx += xv; sy += yv; sz += zv;
        sxx = fmaf(xv, xv, sxx); sxy = fmaf(xv, yv, sxy); sxz = fmaf(xv, zv, sxz);
        syy = fmaf(yv, yv, syy); syz = fmaf(yv, zv, syz); szz = fmaf(zv, zv, szz);
    }
    float cntf = (float)(shi - slo + 1);
    float rin = 1.f / cntf;
    float mx = sx * rin, my = sy * rin, mz = sz * rin;
    const float inv23 = 1.f / 23.f;
    float c00 = (sxx - sx * mx) * inv23;
    float c01 = (sxy - sx * my) * inv23;
    float c02 = (sxz - sx * mz) * inv23;
    float c11 = (syy - sy * my) * inv23;
    float c12 = (syz - sy * mz) * inv23;
    float c22 = (szz - sz * mz) * inv23;
    float feat[12];
    feat[0] = xs[(t + 12) * 3 + 0];
    feat[1] = xs[(t + 12) * 3 + 1];
    feat[2] = xs[(t + 12) * 3 + 2];
    feat[3] = c00; feat[4] = c01; feat[5]  = c02;
    feat[6] = c01; feat[7] = c11; feat[8]  = c12;
    feat[9] = c02; feat[10] = c12; feat[11] = c22;
    float dv = dinv[p];
    unsigned int* hp = (unsigned int*)(hs1 + (size_t)p * 64);
    for (int c = 0; c < 64; c += 2) {
        float a0 = Bl[c], a1 = Bl[c + 1];
        #pragma unroll
        for (int i = 0; i < 12; i++) {
            a0 = fmaf(feat[i], Wl[i * 64 + c], a0);
            a1 = fmaf(feat[i], Wl[i * 64 + c + 1], a1);
        }
        unsigned int pk = (unsigned int)f2bf(dv * selu_f(a0)) |
                          ((unsigned int)f2bf(dv * selu_f(a1)) << 16);
        hp[c >> 1] = pk;
    }
}

// ---------------------------------------------------------------------------
// Graph prep
// ---------------------------------------------------------------------------
__global__ void zero2_kernel(int* __restrict__ a, int* __restrict__ b,
                             unsigned int* __restrict__ pad1,
                             unsigned int* __restrict__ pad2, int n) {
    int i = blockIdx.x * blockDim.x + threadIdx.x;
    if (i < n) { a[i] = 0; b[i] = 0; }
    if (i < 32) pad1[i] = 0;   // hs1 sentinel row (64 bf16)
    if (i < 64) pad2[i] = 0;   // hs2 sentinel row (128 bf16)
}

__global__ void count_kernel(const int* __restrict__ dst, int* __restrict__ cnt, int E) {
    int e = blockIdx.x * blockDim.x + threadIdx.x;
    if (e < E) atomicAdd(&cnt[dst[e]], 1);
}

// scan over padded counts ((c+3)&~3), also: dinv = rsqrt(c+1), pad-fill ssrc
// with sentinel index n (zero row).  n == 32768, one block of 1024 threads.
__global__ __launch_bounds__(1024) void scan_kernel(
    const int* __restrict__ cnt, int* __restrict__ indptr,
    float* __restrict__ dinv, int* __restrict__ ssrc, int n) {
    __shared__ int sums[1024];
    int t = threadIdx.x;
    int base = t * 32;
    int local[32], cl[32];
    int s = 0;
    #pragma unroll
    for (int i = 0; i < 32; i++) {
        int c = cnt[base + i];
        cl[i] = c;
        local[i] = s;
        s += (c + 3) & ~3;
        dinv[base + i] = rsqrtf((float)(c + 1));
    }
    sums[t] = s;
    __syncthreads();
    for (int off = 1; off < 1024; off <<= 1) {
        int v = (t >= off) ? sums[t - off] : 0;
        __syncthreads();
        sums[t] += v;
        __syncthreads();
    }
    int off = sums[t] - s;  // exclusive prefix for this chunk
    #pragma unroll
    for (int i = 0; i < 32; i++) {
        int ip = off + local[i];
        indptr[base + i] = ip;
        int c = cl[i], pc = (c + 3) & ~3;
        for (int k = c; k < pc; k++) ssrc[ip + k] = n;  // sentinel
    }
    if (t == 1023) indptr[n] = sums[1023];
}

__global__ void scatter_kernel(const int* __restrict__ src, const int* __restrict__ dst,
                               const int* __restrict__ indptr, int* __restrict__ cursor,
                               int* __restrict__ ssrc, int E) {
    int e = blockIdx.x * blockDim.x + threadIdx.x;
    if (e < E) {
        int d = dst[e];
        int pos = atomicAdd(&cursor[d], 1);
        ssrc[indptr[d] + pos] = src[e];
    }
}

// ---------------------------------------------------------------------------
// Aggregation: out[d] = dinv[d] * ( hs[d] + sum_{s in N(d)} hs[s] )  where
// hs = dinv .* h (prescaled bf16).  8 channels (one uint4) per thread.
// CSR rows padded to multiples of 4 with sentinel zero-row -> branchless loop.
// ---------------------------------------------------------------------------
template <int C>
__global__ __launch_bounds__(256) void agg_kernel(
    const unsigned short* __restrict__ hs, const float* __restrict__ dinv,
    const int* __restrict__ indptr, const int* __restrict__ ssrc,
    unsigned short* __restrict__ out, int n_nodes) {
    constexpr int TPN = C / 8;  // threads per node (uint4 each)
    int node = blockIdx.x * (256 / TPN) + threadIdx.x / TPN;
    int cq = threadIdx.x % TPN;
    if (node >= n_nodes) return;
    const uint4* hp = (const uint4*)hs;
    float a[8];
    acc8(a, hp[(size_t)node * TPN + cq]);  // wrong: acc8 adds; init first
    // (re-init properly)
    {
        uint4 u = hp[(size_t)node * TPN + cq];
        a[0] = bflo(u.x); a[1] = bfhi(u.x);
        a[2] = bflo(u.y); a[3] = bfhi(u.y);
        a[4] = bflo(u.z); a[5] = bfhi(u.z);
        a[6] = bflo(u.w); a[7] = bfhi(u.w);
    }
    int beg = indptr[node], end = indptr[node + 1];
    for (int j = beg; j < end; j += 4) {
        int s0 = ssrc[j + 0], s1 = ssrc[j + 1];
        int s2 = ssrc[j + 2], s3 = ssrc[j + 3];
        uint4 v0 = hp[(size_t)s0 * TPN + cq];
        uint4 v1 = hp[(size_t)s1 * TPN + cq];
        uint4 v2 = hp[(size_t)s2 * TPN + cq];
        uint4 v3 = hp[(size_t)s3 * TPN + cq];
        acc8(a, v0); acc8(a, v1); acc8(a, v2); acc8(a, v3);
    }
    float dv = dinv[node];
    uint4 pk;
    pk.x = (unsigned int)f2bf(a[0] * dv) | ((unsigned int)f2bf(a[1] * dv) << 16);
    pk.y = (unsigned int)f2bf(a[2] * dv) | ((unsigned int)f2bf(a[3] * dv) << 16);
    pk.z = (unsigned int)f2bf(a[4] * dv) | ((unsigned int)f2bf(a[5] * dv) << 16);
    pk.w = (unsigned int)f2bf(a[6] * dv) | ((unsigned int)f2bf(a[7] * dv) << 16);
    ((uint4*)out)[(size_t)node * TPN + cq] = pk;
}

// ---------------------------------------------------------------------------
// Pack W [K][N] f32 -> bf16 B-fragments for mfma_f32_16x16x32_bf16.
// Fragment f = nt*(K/32)+ks holds lane l element j = W[ks*32+(l>>4)*8+j][nt*16+(l&15)].
// Blocks 0..15 -> W1 (64x128); blocks 16..143 -> W2 (128x512).
// ---------------------------------------------------------------------------
__global__ void packW_kernel(const float* __restrict__ W1, unsigned short* __restrict__ Wp1,
                             const float* __restrict__ W2, unsigned short* __restrict__ Wp2) {
    int fb = blockIdx.x;
    const float* W; unsigned short* Wp; int K, N, f;
    if (fb < 16) { W = W1; Wp = Wp1; K = 64; N = 128; f = fb; }
    else         { W = W2; Wp = Wp2; K = 128; N = 512; f = fb - 16; }
    int l = threadIdx.x;  // 0..63
    int KS = K / 32;
    int nt = f / KS, ks = f % KS;
    int ncol = nt * 16 + (l & 15);
    int k0 = ks * 32 + (l >> 4) * 8;
    unsigned short v[8];
    #pragma unroll
    for (int j = 0; j < 8; j++) v[j] = f2bf(W[(size_t)(k0 + j) * N + ncol]);
    *(uint4*)&Wp[((size_t)f * 64 + l) * 8] = *(uint4*)v;
}

// ---------------------------------------------------------------------------
// MFMA bf16 GEMM: out = f(A[M,KTOT]bf16 @ W[KTOT,Nfull] + bias)
// Block: 256 thr (4 waves), tile 128 rows x 128 cols. Wave w: rows w*32..w*32+31.
// MODE 1: per-tile column max of selu(...)        -> pmax[blockIdx.x][Nfull]
// MODE 2: bf16 rows dinv[row]*selu(...)           -> outh
// ---------------------------------------------------------------------------
template <int KTOT, int MODE>
__global__ __launch_bounds__(256) void mfma_gemm_kernel(
    const unsigned short* __restrict__ A, const unsigned short* __restrict__ Wp,
    const float* __restrict__ bias, float* __restrict__ pmax,
    unsigned short* __restrict__ outh, const float* __restrict__ dinv, int Nfull) {
    constexpr int KS = KTOT / 32;      // k-steps
    constexpr int LDA = KTOT + 8;      // padded LDS row stride (bf16 units)
    constexpr int CPR = KTOT / 8;      // 16B chunks per row
    __shared__ unsigned short As[128 * LDA];
    int t = threadIdx.x;
    int wave = t >> 6, l = t & 63;
    int ml = l & 15, q = l >> 4;
    int R0 = blockIdx.x * 128;
    int cb = blockIdx.y * 128;

    // stage A tile (128 rows x KTOT) into padded LDS
    for (int c = t; c < 128 * CPR; c += 256) {
        int row = c / CPR, off = c % CPR;
        *(uint4*)&As[row * LDA + off * 8] =
            *(const uint4*)&A[(size_t)(R0 + row) * KTOT + off * 8];
    }
    __syncthreads();

    f32x4 acc[2][8];
    #pragma unroll
    for (int mf = 0; mf < 2; mf++)
        #pragma unroll
        for (int nf = 0; nf < 8; nf++) acc[mf][nf] = (f32x4){0.f, 0.f, 0.f, 0.f};

    const bf16x8* wp8 = (const bf16x8*)Wp;
    int wr = wave * 32;
    #pragma unroll
    for (int ks = 0; ks < KS; ks++) {
        bf16x8 af[2];
        #pragma unroll
        for (int mf = 0; mf < 2; mf++)
            af[mf] = *(const bf16x8*)&As[(wr + mf * 16 + ml) * LDA + ks * 32 + q * 8];
        bf16x8 bf[8];
        #pragma unroll
        for (int nf = 0; nf < 8; nf++)
            bf[nf] = wp8[(size_t)(((cb >> 4) + nf) * KS + ks) * 64 + l];
        #pragma unroll
        for (int mf = 0; mf < 2; mf++)
            #pragma unroll
            for (int nf = 0; nf < 8; nf++)
                acc[mf][nf] = __builtin_amdgcn_mfma_f32_16x16x32_bf16(
                    af[mf], bf[nf], acc[mf][nf], 0, 0, 0);
    }

    if (MODE == 1) {
        // selu + column max; C/D layout: col = ml, row = q*4 + r
        float cmax[8];
        #pragma unroll
        for (int nf = 0; nf < 8; nf++) {
            float bj = bias[cb + nf * 16 + ml];
            float v = -INFINITY;
            #pragma unroll
            for (int mf = 0; mf < 2; mf++)
                #pragma unroll
                for (int r = 0; r < 4; r++)
                    v = fmaxf(v, selu_f(acc[mf][nf][r] + bj));
            v = fmaxf(v, __shfl_xor(v, 16, 64));
            v = fmaxf(v, __shfl_xor(v, 32, 64));
            cmax[nf] = v;
        }
        __syncthreads();  // before reusing As as f32 scratch
        float* redf = (float*)As;  // [4 waves][128 cols]
        if (ml == l) {  // lanes 0..15
            #pragma unroll
            for (int nf = 0; nf < 8; nf++) redf[wave * 128 + nf * 16 + l] = cmax[nf];
        }
        __syncthreads();
        if (t < 128) {
            float v = redf[t];
            v = fmaxf(v, redf[128 + t]);
            v = fmaxf(v, redf[256 + t]);
            v = fmaxf(v, redf[384 + t]);
            pmax[(size_t)blockIdx.x * Nfull + cb + t] = v;
        }
    } else {
        // dinv[row]*selu(...) -> bf16
        float bj[8];
        #pragma unroll
        for (int nf = 0; nf < 8; nf++) bj[nf] = bias[cb + nf * 16 + ml];
        #pragma unroll
        for (int mf = 0; mf < 2; mf++) {
            #pragma unroll
            for (int r = 0; r < 4; r++) {
                int row = R0 + wr + mf * 16 + q * 4 + r;
                float dv = dinv[row];
                #pragma unroll
                for (int nf = 0; nf < 8; nf++) {
                    float v = dv * selu_f(acc[mf][nf][r] + bj[nf]);
                    outh[(size_t)row * Nfull + cb + nf * 16 + ml] = f2bf(v);
                }
            }
        }
    }
}

// ---------------------------------------------------------------------------
// lat: m[b][c] = max over 32 pmax tiles; lat = selu(m @ w_e2 + b_e2);
// latw1 = lat @ w_d1[:512] + b_d1; latw2 = lat @ w_d2[:512] + b_d2.
// One block per batch.
// ---------------------------------------------------------------------------
__global__ __launch_bounds__(256) void lat_kernel(
    const float* __restrict__ pmax, const float* __restrict__ w_e2,
    const float* __restrict__ b_e2, const float* __restrict__ w_d1,
    const float* __restrict__ b_d1, const float* __restrict__ w_d2,
    const float* __restrict__ b_d2, float* __restrict__ latw1,
    float* __restrict__ latw2) {
    int b = blockIdx.x;
    int t = threadIdx.x;
    __shared__ float ml[512], ll[512];
    __shared__ float red[6][256];
    for (int c = t; c < 512; c += 256) {
        const float* p = pmax + (size_t)(b * 32) * 512 + c;
        float v = -INFINITY;
        #pragma unroll
        for (int k = 0; k < 32; k++) v = fmaxf(v, p[k * 512]);
        ml[c] = v;
    }
    __syncthreads();
    for (int cc = 0; cc < 2; cc++) {
        int c = t + cc * 256;
        float acc = b_e2[c];
        for (int k = 0; k < 512; k++) acc = fmaf(ml[k], w_e2[k * 512 + c], acc);
        ll[c] = selu_f(acc);
    }
    __syncthreads();
    float p[6] = {0.f, 0.f, 0.f, 0.f, 0.f, 0.f};
    for (int k = t; k < 512; k += 256) {
        float lv = ll[k];
        #pragma unroll
        for (int j = 0; j < 3; j++) {
            p[j]     = fmaf(lv, w_d1[k * 3 + j], p[j]);
            p[3 + j] = fmaf(lv, w_d2[k * 3 + j], p[3 + j]);
        }
    }
    #pragma unroll
    for (int j = 0; j < 6; j++) red[j][t] = p[j];
    __syncthreads();
    for (int s = 128; s > 0; s >>= 1) {
        if (t < s) {
            #pragma unroll
            for (int j = 0; j < 6; j++) red[j][t] += red[j][t + s];
        }
        __syncthreads();
    }
    if (t < 3) {
        latw1[b * 3 + t] = red[t][0] + b_d1[t];
        latw2[b * 3 + t] = red[3 + t][0] + b_d2[t];
    }
}

// ---------------------------------------------------------------------------
// decoder: per point, grid coords + two 3-wide folds
// ---------------------------------------------------------------------------
__global__ void decode_kernel(const float* __restrict__ latw1, const float* __restrict__ latw2,
                              const float* __restrict__ w_d1, const float* __restrict__ w_d2,
                              float* __restrict__ out, int total) {
    int p = blockIdx.x * blockDim.x + threadIdx.x;
    if (p >= total) return;
    int b = p >> 12;
    int n = p & 4095;
    int i = n / 46;
    int j = n - i * 46;
    float y0 = fmaf((float)i, 119.f / 90.f, 1.f);
    float y1 = fmaf((float)j, 59.f / 45.f, 1.f);
    float k0 = selu_f(latw1[b * 3 + 0] + y0 * w_d1[1536 + 0] + y1 * w_d1[1539 + 0]);
    float k1 = selu_f(latw1[b * 3 + 1] + y0 * w_d1[1536 + 1] + y1 * w_d1[1539 + 1]);
    float k2 = selu_f(latw1[b * 3 + 2] + y0 * w_d1[1536 + 2] + y1 * w_d1[1539 + 2]);
    float o0 = selu_f(latw2[b * 3 + 0] + k0 * w_d2[1536 + 0] + k1 * w_d2[1539 + 0] + k2 * w_d2[1542 + 0]);
    float o1 = selu_f(latw2[b * 3 + 1] + k0 * w_d2[1536 + 1] + k1 * w_d2[1539 + 1] + k2 * w_d2[1542 + 1]);
    float o2 = selu_f(latw2[b * 3 + 2] + k0 * w_d2[1536 + 2] + k1 * w_d2[1539 + 2] + k2 * w_d2[1542 + 2]);
    out[(size_t)p * 3 + 0] = o0;
    out[(size_t)p * 3 + 1] = o1;
    out[(size_t)p * 3 + 2] = o2;
}

// ---------------------------------------------------------------------------
extern "C" void kernel_launch(void* const* d_in, const int* in_sizes, int n_in,
                              void* d_out, int out_size, void* d_ws, size_t ws_size,
                              hipStream_t stream) {
    const float* x    = (const float*)d_in[0];
    const int*   knn  = (const int*)d_in[1];
    const float* w_e1 = (const float*)d_in[2];
    const float* b_e1 = (const float*)d_in[3];
    const float* w_g1 = (const float*)d_in[4];
    const float* b_g1 = (const float*)d_in[5];
    const float* w_g2 = (const float*)d_in[6];
    const float* b_g2 = (const float*)d_in[7];
    const float* w_e2 = (const float*)d_in[8];
    const float* b_e2 = (const float*)d_in[9];
    const float* w_d1 = (const float*)d_in[10];
    const float* b_d1 = (const float*)d_in[11];
    const float* w_d2 = (const float*)d_in[12];
    const float* b_d2 = (const float*)d_in[13];
    float* out = (float*)d_out;

    const int BN = in_sizes[0] / 3;   // 32768
    const int E  = in_sizes[1] / 2;   // 524288
    const int Bb = BN / 4096;         // 8
    const int* src = knn;
    const int* dst = knn + E;

    size_t off = 0;
    auto alloc = [&](size_t bytes) -> void* {
        void* p = (char*)d_ws + off;
        off += (bytes + 255) & ~(size_t)255;
        return p;
    };
    unsigned short* hs1 = (unsigned short*)alloc((size_t)(BN + 1) * 64 * 2);
    unsigned short* hs2 = (unsigned short*)alloc((size_t)(BN + 1) * 128 * 2);
    unsigned short* a1  = (unsigned short*)alloc((size_t)BN * 64 * 2);
    unsigned short* a2  = (unsigned short*)alloc((size_t)BN * 128 * 2);
    unsigned short* Wp1 = (unsigned short*)alloc((size_t)16 * 64 * 8 * 2);
    unsigned short* Wp2 = (unsigned short*)alloc((size_t)128 * 64 * 8 * 2);
    float* pmax   = (float*)alloc((size_t)(BN / 128) * 512 * 4);
    float* latw1  = (float*)alloc((size_t)Bb * 3 * 4);
    float* latw2  = (float*)alloc((size_t)Bb * 3 * 4);
    float* dinv   = (float*)alloc((size_t)BN * 4);
    int*   cnt    = (int*)alloc((size_t)BN * 4);
    int*   cursor = (int*)alloc((size_t)BN * 4);
    int*   indptr = (int*)alloc((size_t)(BN + 1) * 4);
    int*   ssrc   = (int*)alloc((size_t)(E + 3 * BN) * 4);
    (void)ws_size;

    // weight packs (independent of graph)
    packW_kernel<<<144, 64, 0, stream>>>(w_g1, Wp1, w_g2, Wp2);

    // graph prep (also zero the sentinel rows of hs1/hs2)
    zero2_kernel<<<(BN + 255) / 256, 256, 0, stream>>>(
        cnt, cursor, (unsigned int*)(hs1 + (size_t)BN * 64),
        (unsigned int*)(hs2 + (size_t)BN * 128), BN);
    count_kernel<<<(E + 255) / 256, 256, 0, stream>>>(dst, cnt, E);
    scan_kernel<<<1, 1024, 0, stream>>>(cnt, indptr, dinv, ssrc, BN);
    scatter_kernel<<<(E + 255) / 256, 256, 0, stream>>>(src, dst, indptr, cursor, ssrc, E);

    // encoder (writes dinv-prescaled bf16 hs1)
    cov_enc_kernel<<<(BN + 255) / 256, 256, 0, stream>>>(x, w_e1, b_e1, dinv, hs1, BN);

    // GCN1: aggregate(64, uint4 gather) -> MFMA gemm, epilogue writes bf16 hs2
    agg_kernel<64><<<BN / 32, 256, 0, stream>>>(hs1, dinv, indptr, ssrc, a1, BN);
    mfma_gemm_kernel<64, 2><<<dim3(BN / 128, 1), 256, 0, stream>>>(
        a1, Wp1, b_g1, nullptr, hs2, dinv, 128);

    // GCN2: aggregate(128, uint4 gather) -> MFMA gemm + selu + fused column-max
    agg_kernel<128><<<BN / 16, 256, 0, stream>>>(hs2, dinv, indptr, ssrc, a2, BN);
    mfma_gemm_kernel<128, 1><<<dim3(BN / 128, 4), 256, 0, stream>>>(
        a2, Wp2, b_g2, pmax, nullptr, nullptr, 512);

    // max-pool + latent + per-batch decoder coefficients (fused)
    lat_kernel<<<Bb, 256, 0, stream>>>(pmax, w_e2, b_e2, w_d1, b_d1, w_d2, b_d2, latw1, latw2);

    // decoder
    decode_kernel<<<(BN + 255) / 256, 256, 0, stream>>>(latw1, latw2, w_d1, w_d2, out, BN);
}

// Round 5
// 255.680 us; speedup vs baseline: 1.2233x; 1.2233x over previous
//
#include <hip/hip_runtime.h>
#include <math.h>

#define SELU_SCALE 1.0507009873554804934193349852946f
#define SELU_ALPHA 1.6732632423543772848170429916717f

typedef short bf16x8 __attribute__((ext_vector_type(8)));
typedef float f32x4 __attribute__((ext_vector_type(4)));

__device__ __forceinline__ float selu_f(float x) {
    return SELU_SCALE * (x > 0.f ? x : SELU_ALPHA * expm1f(x));
}

__device__ __forceinline__ unsigned short f2bf(float f) {
    unsigned int u = __float_as_uint(f);
    u += 0x7FFF + ((u >> 16) & 1);  // round-to-nearest-even
    return (unsigned short)(u >> 16);
}
__device__ __forceinline__ float bflo(unsigned int u) { return __uint_as_float(u << 16); }
__device__ __forceinline__ float bfhi(unsigned int u) { return __uint_as_float(u & 0xFFFF0000u); }

__device__ __forceinline__ void acc8(float* a, uint4 v) {
    a[0] += bflo(v.x); a[1] += bfhi(v.x);
    a[2] += bflo(v.y); a[3] += bfhi(v.y);
    a[4] += bflo(v.z); a[5] += bfhi(v.z);
    a[6] += bflo(v.w); a[7] += bfhi(v.w);
}

// ---------------------------------------------------------------------------
// K1: local covariance (window 25, divisor 23) + [x,cov] @ w_e1 + b_e1, selu,
// prescaled by dinv[p], stored bf16.  LDS-staged x tile, single-pass moments.
// ---------------------------------------------------------------------------
__global__ __launch_bounds__(256) void cov_enc_kernel(
    const float* __restrict__ x, const float* __restrict__ w_e1,
    const float* __restrict__ b_e1, const float* __restrict__ dinv,
    unsigned short* __restrict__ hs1, int BN) {
    __shared__ float Wl[12 * 64];
    __shared__ float Bl[64];
    __shared__ float xs[280 * 3];
    int t = threadIdx.x;
    for (int i = t; i < 768; i += 256) Wl[i] = w_e1[i];
    if (t < 64) Bl[t] = b_e1[t];
    int p0 = blockIdx.x * 256;
    int n0 = p0 & 4095;
    const float* xb = x + (size_t)(p0 - n0) * 3;  // batch base (256 | 4096)
    for (int idx = t; idx < 840; idx += 256) {
        int slot = idx / 3, d = idx - slot * 3;
        int g = n0 - 12 + slot;
        g = g < 0 ? 0 : (g > 4095 ? 4095 : g);
        xs[idx] = xb[g * 3 + d];
    }
    __syncthreads();
    int p = p0 + t;
    int n = n0 + t;
    int lo = n - 12 < 0 ? 0 : n - 12;
    int hi = n + 12 > 4095 ? 4095 : n + 12;
    int slo = lo - n0 + 12, shi = hi - n0 + 12;
    float sx = 0.f, sy = 0.f, sz = 0.f;
    float sxx = 0.f, sxy = 0.f, sxz = 0.f, syy = 0.f, syz = 0.f, szz = 0.f;
    for (int s = slo; s <= shi; s++) {
        float xv = xs[s * 3 + 0], yv = xs[s * 3 + 1], zv = xs[s * 3 + 2];
        sx += xv; sy += yv; sz += zv;
        sxx = fmaf(xv, xv, sxx); sxy = fmaf(xv, yv, sxy); sxz = fmaf(xv, zv, sxz);
        syy = fmaf(yv, yv, syy); syz = fmaf(yv, zv, syz); szz = fmaf(zv, zv, szz);
    }
    float cntf = (float)(shi - slo + 1);
    float rin = 1.f / cntf;
    float mx = sx * rin, my = sy * rin, mz = sz * rin;
    const float inv23 = 1.f / 23.f;
    float c00 = (sxx - sx * mx) * inv23;
    float c01 = (sxy - sx * my) * inv23;
    float c02 = (sxz - sx * mz) * inv23;
    float c11 = (syy - sy * my) * inv23;
    float c12 = (syz - sy * mz) * inv23;
    float c22 = (szz - sz * mz) * inv23;
    float feat[12];
    feat[0] = xs[(t + 12) * 3 + 0];
    feat[1] = xs[(t + 12) * 3 + 1];
    feat[2] = xs[(t + 12) * 3 + 2];
    feat[3] = c00; feat[4] = c01; feat[5]  = c02;
    feat[6] = c01; feat[7] = c11; feat[8]  = c12;
    feat[9] = c02; feat[10] = c12; feat[11] = c22;
    float dv = dinv[p];
    unsigned int* hp = (unsigned int*)(hs1 + (size_t)p * 64);
    for (int c = 0; c < 64; c += 2) {
        float a0 = Bl[c], a1 = Bl[c + 1];
        #pragma unroll
        for (int i = 0; i < 12; i++) {
            a0 = fmaf(feat[i], Wl[i * 64 + c], a0);
            a1 = fmaf(feat[i], Wl[i * 64 + c + 1], a1);
        }
        unsigned int pk = (unsigned int)f2bf(dv * selu_f(a0)) |
                          ((unsigned int)f2bf(dv * selu_f(a1)) << 16);
        hp[c >> 1] = pk;
    }
}

// ---------------------------------------------------------------------------
// Graph prep
// ---------------------------------------------------------------------------
__global__ void zero2_kernel(int* __restrict__ a, int* __restrict__ b,
                             unsigned int* __restrict__ pad1,
                             unsigned int* __restrict__ pad2, int n) {
    int i = blockIdx.x * blockDim.x + threadIdx.x;
    if (i < n) { a[i] = 0; b[i] = 0; }
    if (i < 32) pad1[i] = 0;   // hs1 sentinel row (64 bf16)
    if (i < 64) pad2[i] = 0;   // hs2 sentinel row (128 bf16)
}

__global__ void count_kernel(const int* __restrict__ dst, int* __restrict__ cnt, int E) {
    int e = blockIdx.x * blockDim.x + threadIdx.x;
    if (e < E) atomicAdd(&cnt[dst[e]], 1);
}

// --- 3-phase parallel exclusive scan over padded counts ((c+3)&~3) ---
// A: per-block (256 elems) sums
__global__ __launch_bounds__(256) void scanA_kernel(const int* __restrict__ cnt,
                                                    int* __restrict__ blockSums) {
    __shared__ int red[256];
    int t = threadIdx.x;
    int c = cnt[blockIdx.x * 256 + t];
    red[t] = (c + 3) & ~3;
    __syncthreads();
    for (int s = 128; s > 0; s >>= 1) {
        if (t < s) red[t] += red[t + s];
        __syncthreads();
    }
    if (t == 0) blockSums[blockIdx.x] = red[0];
}

// B: exclusive scan of 128 block sums (one block)
__global__ __launch_bounds__(128) void scanB_kernel(int* __restrict__ blockSums) {
    __shared__ int s[128];
    int t = threadIdx.x;
    int orig = blockSums[t];
    s[t] = orig;
    __syncthreads();
    for (int off = 1; off < 128; off <<= 1) {
        int v = t >= off ? s[t - off] : 0;
        __syncthreads();
        s[t] += v;
        __syncthreads();
    }
    blockSums[t] = s[t] - orig;  // exclusive
}

// C: block-local scan + offset -> indptr, dinv, sentinel pad-fill of ssrc
__global__ __launch_bounds__(256) void scanC_kernel(
    const int* __restrict__ cnt, const int* __restrict__ blockOffs,
    int* __restrict__ indptr, float* __restrict__ dinv, int* __restrict__ ssrc, int n) {
    __shared__ int sc[256];
    int t = threadIdx.x;
    int i = blockIdx.x * 256 + t;
    int c = cnt[i];
    int pc = (c + 3) & ~3;
    sc[t] = pc;
    __syncthreads();
    for (int off = 1; off < 256; off <<= 1) {
        int v = t >= off ? sc[t - off] : 0;
        __syncthreads();
        sc[t] += v;
        __syncthreads();
    }
    int ip = blockOffs[blockIdx.x] + sc[t] - pc;  // exclusive position
    indptr[i] = ip;
    dinv[i] = rsqrtf((float)(c + 1));
    for (int k = c; k < pc; k++) ssrc[ip + k] = n;  // sentinel zero-row
    if (i == n - 1) indptr[n] = blockOffs[blockIdx.x] + sc[t];
}

__global__ void scatter_kernel(const int* __restrict__ src, const int* __restrict__ dst,
                               const int* __restrict__ indptr, int* __restrict__ cursor,
                               int* __restrict__ ssrc, int E) {
    int e = blockIdx.x * blockDim.x + threadIdx.x;
    if (e < E) {
        int d = dst[e];
        int pos = atomicAdd(&cursor[d], 1);
        ssrc[indptr[d] + pos] = src[e];
    }
}

// ---------------------------------------------------------------------------
// Aggregation: out[d] = dinv[d] * ( hs[d] + sum_{s in N(d)} hs[s] )  where
// hs = dinv .* h (prescaled bf16).  8 channels (one uint4) per thread.
// CSR rows padded to multiples of 4 with sentinel zero-row -> branchless loop.
// ---------------------------------------------------------------------------
template <int C>
__global__ __launch_bounds__(256) void agg_kernel(
    const unsigned short* __restrict__ hs, const float* __restrict__ dinv,
    const int* __restrict__ indptr, const int* __restrict__ ssrc,
    unsigned short* __restrict__ out, int n_nodes) {
    constexpr int TPN = C / 8;  // threads per node (uint4 each)
    int node = blockIdx.x * (256 / TPN) + threadIdx.x / TPN;
    int cq = threadIdx.x % TPN;
    if (node >= n_nodes) return;
    const uint4* hp = (const uint4*)hs;
    float a[8];
    {
        uint4 u = hp[(size_t)node * TPN + cq];
        a[0] = bflo(u.x); a[1] = bfhi(u.x);
        a[2] = bflo(u.y); a[3] = bfhi(u.y);
        a[4] = bflo(u.z); a[5] = bfhi(u.z);
        a[6] = bflo(u.w); a[7] = bfhi(u.w);
    }
    int beg = indptr[node], end = indptr[node + 1];
    for (int j = beg; j < end; j += 4) {
        int s0 = ssrc[j + 0], s1 = ssrc[j + 1];
        int s2 = ssrc[j + 2], s3 = ssrc[j + 3];
        uint4 v0 = hp[(size_t)s0 * TPN + cq];
        uint4 v1 = hp[(size_t)s1 * TPN + cq];
        uint4 v2 = hp[(size_t)s2 * TPN + cq];
        uint4 v3 = hp[(size_t)s3 * TPN + cq];
        acc8(a, v0); acc8(a, v1); acc8(a, v2); acc8(a, v3);
    }
    float dv = dinv[node];
    uint4 pk;
    pk.x = (unsigned int)f2bf(a[0] * dv) | ((unsigned int)f2bf(a[1] * dv) << 16);
    pk.y = (unsigned int)f2bf(a[2] * dv) | ((unsigned int)f2bf(a[3] * dv) << 16);
    pk.z = (unsigned int)f2bf(a[4] * dv) | ((unsigned int)f2bf(a[5] * dv) << 16);
    pk.w = (unsigned int)f2bf(a[6] * dv) | ((unsigned int)f2bf(a[7] * dv) << 16);
    ((uint4*)out)[(size_t)node * TPN + cq] = pk;
}

// ---------------------------------------------------------------------------
// Pack W [K][N] f32 -> bf16 B-fragments for mfma_f32_16x16x32_bf16.
// Fragment f = nt*(K/32)+ks holds lane l element j = W[ks*32+(l>>4)*8+j][nt*16+(l&15)].
// Blocks 0..15 -> W1 (64x128); blocks 16..143 -> W2 (128x512).
// ---------------------------------------------------------------------------
__global__ void packW_kernel(const float* __restrict__ W1, unsigned short* __restrict__ Wp1,
                             const float* __restrict__ W2, unsigned short* __restrict__ Wp2) {
    int fb = blockIdx.x;
    const float* W; unsigned short* Wp; int K, N, f;
    if (fb < 16) { W = W1; Wp = Wp1; K = 64; N = 128; f = fb; }
    else         { W = W2; Wp = Wp2; K = 128; N = 512; f = fb - 16; }
    int l = threadIdx.x;  // 0..63
    int KS = K / 32;
    int nt = f / KS, ks = f % KS;
    int ncol = nt * 16 + (l & 15);
    int k0 = ks * 32 + (l >> 4) * 8;
    unsigned short v[8];
    #pragma unroll
    for (int j = 0; j < 8; j++) v[j] = f2bf(W[(size_t)(k0 + j) * N + ncol]);
    *(uint4*)&Wp[((size_t)f * 64 + l) * 8] = *(uint4*)v;
}

// ---------------------------------------------------------------------------
// MFMA bf16 GEMM: out = f(A[M,KTOT]bf16 @ W[KTOT,Nfull] + bias)
// Block: 256 thr (4 waves), tile 128 rows x 128 cols. Wave w: rows w*32..w*32+31.
// MODE 1: per-tile column max of selu(...)        -> pmax[blockIdx.x][Nfull]
// MODE 2: bf16 rows dinv[row]*selu(...)           -> outh
// ---------------------------------------------------------------------------
template <int KTOT, int MODE>
__global__ __launch_bounds__(256) void mfma_gemm_kernel(
    const unsigned short* __restrict__ A, const unsigned short* __restrict__ Wp,
    const float* __restrict__ bias, float* __restrict__ pmax,
    unsigned short* __restrict__ outh, const float* __restrict__ dinv, int Nfull) {
    constexpr int KS = KTOT / 32;      // k-steps
    constexpr int LDA = KTOT + 8;      // padded LDS row stride (bf16 units)
    constexpr int CPR = KTOT / 8;      // 16B chunks per row
    __shared__ unsigned short As[128 * LDA];
    int t = threadIdx.x;
    int wave = t >> 6, l = t & 63;
    int ml = l & 15, q = l >> 4;
    int R0 = blockIdx.x * 128;
    int cb = blockIdx.y * 128;

    // stage A tile (128 rows x KTOT) into padded LDS
    for (int c = t; c < 128 * CPR; c += 256) {
        int row = c / CPR, off = c % CPR;
        *(uint4*)&As[row * LDA + off * 8] =
            *(const uint4*)&A[(size_t)(R0 + row) * KTOT + off * 8];
    }
    __syncthreads();

    f32x4 acc[2][8];
    #pragma unroll
    for (int mf = 0; mf < 2; mf++)
        #pragma unroll
        for (int nf = 0; nf < 8; nf++) acc[mf][nf] = (f32x4){0.f, 0.f, 0.f, 0.f};

    const bf16x8* wp8 = (const bf16x8*)Wp;
    int wr = wave * 32;
    #pragma unroll
    for (int ks = 0; ks < KS; ks++) {
        bf16x8 af[2];
        #pragma unroll
        for (int mf = 0; mf < 2; mf++)
            af[mf] = *(const bf16x8*)&As[(wr + mf * 16 + ml) * LDA + ks * 32 + q * 8];
        bf16x8 bf[8];
        #pragma unroll
        for (int nf = 0; nf < 8; nf++)
            bf[nf] = wp8[(size_t)(((cb >> 4) + nf) * KS + ks) * 64 + l];
        #pragma unroll
        for (int mf = 0; mf < 2; mf++)
            #pragma unroll
            for (int nf = 0; nf < 8; nf++)
                acc[mf][nf] = __builtin_amdgcn_mfma_f32_16x16x32_bf16(
                    af[mf], bf[nf], acc[mf][nf], 0, 0, 0);
    }

    if (MODE == 1) {
        // selu + column max; C/D layout: col = ml, row = q*4 + r
        float cmax[8];
        #pragma unroll
        for (int nf = 0; nf < 8; nf++) {
            float bj = bias[cb + nf * 16 + ml];
            float v = -INFINITY;
            #pragma unroll
            for (int mf = 0; mf < 2; mf++)
                #pragma unroll
                for (int r = 0; r < 4; r++)
                    v = fmaxf(v, selu_f(acc[mf][nf][r] + bj));
            v = fmaxf(v, __shfl_xor(v, 16, 64));
            v = fmaxf(v, __shfl_xor(v, 32, 64));
            cmax[nf] = v;
        }
        __syncthreads();  // before reusing As as f32 scratch
        float* redf = (float*)As;  // [4 waves][128 cols]
        if (ml == l) {  // lanes 0..15
            #pragma unroll
            for (int nf = 0; nf < 8; nf++) redf[wave * 128 + nf * 16 + l] = cmax[nf];
        }
        __syncthreads();
        if (t < 128) {
            float v = redf[t];
            v = fmaxf(v, redf[128 + t]);
            v = fmaxf(v, redf[256 + t]);
            v = fmaxf(v, redf[384 + t]);
            pmax[(size_t)blockIdx.x * Nfull + cb + t] = v;
        }
    } else {
        // dinv[row]*selu(...) -> bf16
        float bj[8];
        #pragma unroll
        for (int nf = 0; nf < 8; nf++) bj[nf] = bias[cb + nf * 16 + ml];
        #pragma unroll
        for (int mf = 0; mf < 2; mf++) {
            #pragma unroll
            for (int r = 0; r < 4; r++) {
                int row = R0 + wr + mf * 16 + q * 4 + r;
                float dv = dinv[row];
                #pragma unroll
                for (int nf = 0; nf < 8; nf++) {
                    float v = dv * selu_f(acc[mf][nf][r] + bj[nf]);
                    outh[(size_t)row * Nfull + cb + nf * 16 + ml] = f2bf(v);
                }
            }
        }
    }
}

// ---------------------------------------------------------------------------
// lat: m[b][c] = max over 32 pmax tiles; lat = selu(m @ w_e2 + b_e2);
// latw1 = lat @ w_d1[:512] + b_d1; latw2 = lat @ w_d2[:512] + b_d2.
// One block per batch.
// ---------------------------------------------------------------------------
__global__ __launch_bounds__(256) void lat_kernel(
    const float* __restrict__ pmax, const float* __restrict__ w_e2,
    const float* __restrict__ b_e2, const float* __restrict__ w_d1,
    const float* __restrict__ b_d1, const float* __restrict__ w_d2,
    const float* __restrict__ b_d2, float* __restrict__ latw1,
    float* __restrict__ latw2) {
    int b = blockIdx.x;
    int t = threadIdx.x;
    __shared__ float ml[512], ll[512];
    __shared__ float red[6][256];
    for (int c = t; c < 512; c += 256) {
        const float* p = pmax + (size_t)(b * 32) * 512 + c;
        float v = -INFINITY;
        #pragma unroll
        for (int k = 0; k < 32; k++) v = fmaxf(v, p[k * 512]);
        ml[c] = v;
    }
    __syncthreads();
    for (int cc = 0; cc < 2; cc++) {
        int c = t + cc * 256;
        float acc = b_e2[c];
        for (int k = 0; k < 512; k++) acc = fmaf(ml[k], w_e2[k * 512 + c], acc);
        ll[c] = selu_f(acc);
    }
    __syncthreads();
    float p[6] = {0.f, 0.f, 0.f, 0.f, 0.f, 0.f};
    for (int k = t; k < 512; k += 256) {
        float lv = ll[k];
        #pragma unroll
        for (int j = 0; j < 3; j++) {
            p[j]     = fmaf(lv, w_d1[k * 3 + j], p[j]);
            p[3 + j] = fmaf(lv, w_d2[k * 3 + j], p[3 + j]);
        }
    }
    #pragma unroll
    for (int j = 0; j < 6; j++) red[j][t] = p[j];
    __syncthreads();
    for (int s = 128; s > 0; s >>= 1) {
        if (t < s) {
            #pragma unroll
            for (int j = 0; j < 6; j++) red[j][t] += red[j][t + s];
        }
        __syncthreads();
    }
    if (t < 3) {
        latw1[b * 3 + t] = red[t][0] + b_d1[t];
        latw2[b * 3 + t] = red[3 + t][0] + b_d2[t];
    }
}

// ---------------------------------------------------------------------------
// decoder: per point, grid coords + two 3-wide folds
// ---------------------------------------------------------------------------
__global__ void decode_kernel(const float* __restrict__ latw1, const float* __restrict__ latw2,
                              const float* __restrict__ w_d1, const float* __restrict__ w_d2,
                              float* __restrict__ out, int total) {
    int p = blockIdx.x * blockDim.x + threadIdx.x;
    if (p >= total) return;
    int b = p >> 12;
    int n = p & 4095;
    int i = n / 46;
    int j = n - i * 46;
    float y0 = fmaf((float)i, 119.f / 90.f, 1.f);
    float y1 = fmaf((float)j, 59.f / 45.f, 1.f);
    float k0 = selu_f(latw1[b * 3 + 0] + y0 * w_d1[1536 + 0] + y1 * w_d1[1539 + 0]);
    float k1 = selu_f(latw1[b * 3 + 1] + y0 * w_d1[1536 + 1] + y1 * w_d1[1539 + 1]);
    float k2 = selu_f(latw1[b * 3 + 2] + y0 * w_d1[1536 + 2] + y1 * w_d1[1539 + 2]);
    float o0 = selu_f(latw2[b * 3 + 0] + k0 * w_d2[1536 + 0] + k1 * w_d2[1539 + 0] + k2 * w_d2[1542 + 0]);
    float o1 = selu_f(latw2[b * 3 + 1] + k0 * w_d2[1536 + 1] + k1 * w_d2[1539 + 1] + k2 * w_d2[1542 + 1]);
    float o2 = selu_f(latw2[b * 3 + 2] + k0 * w_d2[1536 + 2] + k1 * w_d2[1539 + 2] + k2 * w_d2[1542 + 2]);
    out[(size_t)p * 3 + 0] = o0;
    out[(size_t)p * 3 + 1] = o1;
    out[(size_t)p * 3 + 2] = o2;
}

// ---------------------------------------------------------------------------
extern "C" void kernel_launch(void* const* d_in, const int* in_sizes, int n_in,
                              void* d_out, int out_size, void* d_ws, size_t ws_size,
                              hipStream_t stream) {
    const float* x    = (const float*)d_in[0];
    const int*   knn  = (const int*)d_in[1];
    const float* w_e1 = (const float*)d_in[2];
    const float* b_e1 = (const float*)d_in[3];
    const float* w_g1 = (const float*)d_in[4];
    const float* b_g1 = (const float*)d_in[5];
    const float* w_g2 = (const float*)d_in[6];
    const float* b_g2 = (const float*)d_in[7];
    const float* w_e2 = (const float*)d_in[8];
    const float* b_e2 = (const float*)d_in[9];
    const float* w_d1 = (const float*)d_in[10];
    const float* b_d1 = (const float*)d_in[11];
    const float* w_d2 = (const float*)d_in[12];
    const float* b_d2 = (const float*)d_in[13];
    float* out = (float*)d_out;

    const int BN = in_sizes[0] / 3;   // 32768
    const int E  = in_sizes[1] / 2;   // 524288
    const int Bb = BN / 4096;         // 8
    const int* src = knn;
    const int* dst = knn + E;

    size_t off = 0;
    auto alloc = [&](size_t bytes) -> void* {
        void* p = (char*)d_ws + off;
        off += (bytes + 255) & ~(size_t)255;
        return p;
    };
    unsigned short* hs1 = (unsigned short*)alloc((size_t)(BN + 1) * 64 * 2);
    unsigned short* hs2 = (unsigned short*)alloc((size_t)(BN + 1) * 128 * 2);
    unsigned short* a1  = (unsigned short*)alloc((size_t)BN * 64 * 2);
    unsigned short* a2  = (unsigned short*)alloc((size_t)BN * 128 * 2);
    unsigned short* Wp1 = (unsigned short*)alloc((size_t)16 * 64 * 8 * 2);
    unsigned short* Wp2 = (unsigned short*)alloc((size_t)128 * 64 * 8 * 2);
    float* pmax   = (float*)alloc((size_t)(BN / 128) * 512 * 4);
    float* latw1  = (float*)alloc((size_t)Bb * 3 * 4);
    float* latw2  = (float*)alloc((size_t)Bb * 3 * 4);
    float* dinv   = (float*)alloc((size_t)BN * 4);
    int*   cnt    = (int*)alloc((size_t)BN * 4);
    int*   cursor = (int*)alloc((size_t)BN * 4);
    int*   indptr = (int*)alloc((size_t)(BN + 1) * 4);
    int*   bsums  = (int*)alloc((size_t)128 * 4);
    int*   ssrc   = (int*)alloc((size_t)(E + 3 * BN) * 4);
    (void)ws_size;

    // weight packs (independent of graph)
    packW_kernel<<<144, 64, 0, stream>>>(w_g1, Wp1, w_g2, Wp2);

    // graph prep (also zero the sentinel rows of hs1/hs2)
    zero2_kernel<<<(BN + 255) / 256, 256, 0, stream>>>(
        cnt, cursor, (unsigned int*)(hs1 + (size_t)BN * 64),
        (unsigned int*)(hs2 + (size_t)BN * 128), BN);
    count_kernel<<<(E + 255) / 256, 256, 0, stream>>>(dst, cnt, E);
    scanA_kernel<<<BN / 256, 256, 0, stream>>>(cnt, bsums);
    scanB_kernel<<<1, 128, 0, stream>>>(bsums);
    scanC_kernel<<<BN / 256, 256, 0, stream>>>(cnt, bsums, indptr, dinv, ssrc, BN);
    scatter_kernel<<<(E + 255) / 256, 256, 0, stream>>>(src, dst, indptr, cursor, ssrc, E);

    // encoder (writes dinv-prescaled bf16 hs1)
    cov_enc_kernel<<<(BN + 255) / 256, 256, 0, stream>>>(x, w_e1, b_e1, dinv, hs1, BN);

    // GCN1: aggregate(64, uint4 gather) -> MFMA gemm, epilogue writes bf16 hs2
    agg_kernel<64><<<BN / 32, 256, 0, stream>>>(hs1, dinv, indptr, ssrc, a1, BN);
    mfma_gemm_kernel<64, 2><<<dim3(BN / 128, 1), 256, 0, stream>>>(
        a1, Wp1, b_g1, nullptr, hs2, dinv, 128);

    // GCN2: aggregate(128, uint4 gather) -> MFMA gemm + selu + fused column-max
    agg_kernel<128><<<BN / 16, 256, 0, stream>>>(hs2, dinv, indptr, ssrc, a2, BN);
    mfma_gemm_kernel<128, 1><<<dim3(BN / 128, 4), 256, 0, stream>>>(
        a2, Wp2, b_g2, pmax, nullptr, nullptr, 512);

    // max-pool + latent + per-batch decoder coefficients (fused)
    lat_kernel<<<Bb, 256, 0, stream>>>(pmax, w_e2, b_e2, w_d1, b_d1, w_d2, b_d2, latw1, latw2);

    // decoder
    decode_kernel<<<(BN + 255) / 256, 256, 0, stream>>>(latw1, latw2, w_d1, w_d2, out, BN);
}

// Round 6
// 236.140 us; speedup vs baseline: 1.3246x; 1.0827x over previous
//
#include <hip/hip_runtime.h>
#include <math.h>

#define SELU_SCALE 1.0507009873554804934193349852946f
#define SELU_ALPHA 1.6732632423543772848170429916717f

typedef short bf16x8 __attribute__((ext_vector_type(8)));
typedef float f32x4 __attribute__((ext_vector_type(4)));

__device__ __forceinline__ float selu_f(float x) {
    return SELU_SCALE * (x > 0.f ? x : SELU_ALPHA * expm1f(x));
}

__device__ __forceinline__ unsigned short f2bf(float f) {
    unsigned int u = __float_as_uint(f);
    u += 0x7FFF + ((u >> 16) & 1);  // round-to-nearest-even
    return (unsigned short)(u >> 16);
}
__device__ __forceinline__ float bflo(unsigned int u) { return __uint_as_float(u << 16); }
__device__ __forceinline__ float bfhi(unsigned int u) { return __uint_as_float(u & 0xFFFF0000u); }

__device__ __forceinline__ void acc8(float* a, uint4 v) {
    a[0] += bflo(v.x); a[1] += bfhi(v.x);
    a[2] += bflo(v.y); a[3] += bfhi(v.y);
    a[4] += bflo(v.z); a[5] += bfhi(v.z);
    a[6] += bflo(v.w); a[7] += bfhi(v.w);
}

__device__ __forceinline__ uint4 pack8(const float* a, float dv) {
    uint4 pk;
    pk.x = (unsigned int)f2bf(a[0] * dv) | ((unsigned int)f2bf(a[1] * dv) << 16);
    pk.y = (unsigned int)f2bf(a[2] * dv) | ((unsigned int)f2bf(a[3] * dv) << 16);
    pk.z = (unsigned int)f2bf(a[4] * dv) | ((unsigned int)f2bf(a[5] * dv) << 16);
    pk.w = (unsigned int)f2bf(a[6] * dv) | ((unsigned int)f2bf(a[7] * dv) << 16);
    return pk;
}

// ---------------------------------------------------------------------------
// prep: blocks 0..127 zero cnt; block 128 zeros hs1/hs2 sentinel rows;
// blocks 129..272 pack weights into MFMA B-fragment layout.
// Fragment f = nt*(K/32)+ks holds lane l elem j = W[ks*32+(l>>4)*8+j][nt*16+(l&15)].
// ---------------------------------------------------------------------------
__global__ __launch_bounds__(256) void prep_kernel(
    int* __restrict__ cnt, unsigned int* __restrict__ pad1,
    unsigned int* __restrict__ pad2,
    const float* __restrict__ W1, unsigned short* __restrict__ Wp1,
    const float* __restrict__ W2, unsigned short* __restrict__ Wp2) {
    int b = blockIdx.x;
    int t = threadIdx.x;
    if (b < 128) {
        cnt[b * 256 + t] = 0;
    } else if (b == 128) {
        if (t < 32) pad1[t] = 0;   // hs1 sentinel row (64 bf16)
        if (t < 64) pad2[t] = 0;   // hs2 sentinel row (128 bf16)
    } else {
        if (t >= 64) return;
        int fb = b - 129;
        const float* W; unsigned short* Wp; int K, N, f;
        if (fb < 16) { W = W1; Wp = Wp1; K = 64; N = 128; f = fb; }
        else         { W = W2; Wp = Wp2; K = 128; N = 512; f = fb - 16; }
        int l = t;  // 0..63
        int KS = K / 32;
        int nt = f / KS, ks = f % KS;
        int ncol = nt * 16 + (l & 15);
        int k0 = ks * 32 + (l >> 4) * 8;
        unsigned short v[8];
        #pragma unroll
        for (int j = 0; j < 8; j++) v[j] = f2bf(W[(size_t)(k0 + j) * N + ncol]);
        *(uint4*)&Wp[((size_t)f * 64 + l) * 8] = *(uint4*)v;
    }
}

// count degrees AND record each edge's slot within its destination's segment
__global__ void count_kernel(const int* __restrict__ dst, int* __restrict__ cnt,
                             int* __restrict__ epos, int E) {
    int e = blockIdx.x * blockDim.x + threadIdx.x;
    if (e < E) epos[e] = atomicAdd(&cnt[dst[e]], 1);
}

// --- parallel exclusive scan over padded counts ((c+7)&~7), 2 kernels ---
__global__ __launch_bounds__(256) void scanA_kernel(const int* __restrict__ cnt,
                                                    int* __restrict__ blockSums) {
    __shared__ int red[256];
    int t = threadIdx.x;
    int c = cnt[blockIdx.x * 256 + t];
    red[t] = (c + 7) & ~7;
    __syncthreads();
    for (int s = 128; s > 0; s >>= 1) {
        if (t < s) red[t] += red[t + s];
        __syncthreads();
    }
    if (t == 0) blockSums[blockIdx.x] = red[0];
}

// block-local scan + inline scan of the 128 block sums -> indptr, dinv,
// sentinel pad-fill of ssrc
__global__ __launch_bounds__(256) void scanC_kernel(
    const int* __restrict__ cnt, const int* __restrict__ bsums,
    int* __restrict__ indptr, float* __restrict__ dinv, int* __restrict__ ssrc, int n) {
    __shared__ int sc[256];
    __shared__ int bs[128];
    int t = threadIdx.x;
    int ownSum = bsums[blockIdx.x];
    if (t < 128) bs[t] = bsums[t];
    int i = blockIdx.x * 256 + t;
    int c = cnt[i];
    int pc = (c + 7) & ~7;
    sc[t] = pc;
    __syncthreads();
    for (int off = 1; off < 128; off <<= 1) {
        int v = (t >= off && t < 128) ? bs[t - off] : 0;
        __syncthreads();
        if (t < 128) bs[t] += v;
        __syncthreads();
    }
    for (int off = 1; off < 256; off <<= 1) {
        int v = t >= off ? sc[t - off] : 0;
        __syncthreads();
        sc[t] += v;
        __syncthreads();
    }
    int blockOff = bs[blockIdx.x] - ownSum;  // exclusive block offset
    int ip = blockOff + sc[t] - pc;          // exclusive elem offset
    indptr[i] = ip;
    dinv[i] = rsqrtf((float)(c + 1));
    for (int k = c; k < pc; k++) ssrc[ip + k] = n;  // sentinel zero-row
    if (i == n - 1) indptr[n] = blockOff + sc[t];
}

// atomic-free scatter using recorded positions
__global__ void scatter_kernel(const int* __restrict__ src, const int* __restrict__ dst,
                               const int* __restrict__ epos,
                               const int* __restrict__ indptr,
                               int* __restrict__ ssrc, int E) {
    int e = blockIdx.x * blockDim.x + threadIdx.x;
    if (e < E) ssrc[indptr[dst[e]] + epos[e]] = src[e];
}

// ---------------------------------------------------------------------------
// K1: local covariance (window 25, divisor 23) + [x,cov] @ w_e1 + b_e1, selu,
// prescaled by dinv[p], stored bf16.  LDS-staged x tile, single-pass moments.
// ---------------------------------------------------------------------------
__global__ __launch_bounds__(256) void cov_enc_kernel(
    const float* __restrict__ x, const float* __restrict__ w_e1,
    const float* __restrict__ b_e1, const float* __restrict__ dinv,
    unsigned short* __restrict__ hs1, int BN) {
    __shared__ float Wl[12 * 64];
    __shared__ float Bl[64];
    __shared__ float xs[280 * 3];
    int t = threadIdx.x;
    for (int i = t; i < 768; i += 256) Wl[i] = w_e1[i];
    if (t < 64) Bl[t] = b_e1[t];
    int p0 = blockIdx.x * 256;
    int n0 = p0 & 4095;
    const float* xb = x + (size_t)(p0 - n0) * 3;  // batch base (256 | 4096)
    for (int idx = t; idx < 840; idx += 256) {
        int slot = idx / 3, d = idx - slot * 3;
        int g = n0 - 12 + slot;
        g = g < 0 ? 0 : (g > 4095 ? 4095 : g);
        xs[idx] = xb[g * 3 + d];
    }
    __syncthreads();
    int p = p0 + t;
    int n = n0 + t;
    int lo = n - 12 < 0 ? 0 : n - 12;
    int hi = n + 12 > 4095 ? 4095 : n + 12;
    int slo = lo - n0 + 12, shi = hi - n0 + 12;
    float sx = 0.f, sy = 0.f, sz = 0.f;
    float sxx = 0.f, sxy = 0.f, sxz = 0.f, syy = 0.f, syz = 0.f, szz = 0.f;
    for (int s = slo; s <= shi; s++) {
        float xv = xs[s * 3 + 0], yv = xs[s * 3 + 1], zv = xs[s * 3 + 2];
        sx += xv; sy += yv; sz += zv;
        sxx = fmaf(xv, xv, sxx); sxy = fmaf(xv, yv, sxy); sxz = fmaf(xv, zv, sxz);
        syy = fmaf(yv, yv, syy); syz = fmaf(yv, zv, syz); szz = fmaf(zv, zv, szz);
    }
    float cntf = (float)(shi - slo + 1);
    float rin = 1.f / cntf;
    float mx = sx * rin, my = sy * rin, mz = sz * rin;
    const float inv23 = 1.f / 23.f;
    float c00 = (sxx - sx * mx) * inv23;
    float c01 = (sxy - sx * my) * inv23;
    float c02 = (sxz - sx * mz) * inv23;
    float c11 = (syy - sy * my) * inv23;
    float c12 = (syz - sy * mz) * inv23;
    float c22 = (szz - sz * mz) * inv23;
    float feat[12];
    feat[0] = xs[(t + 12) * 3 + 0];
    feat[1] = xs[(t + 12) * 3 + 1];
    feat[2] = xs[(t + 12) * 3 + 2];
    feat[3] = c00; feat[4] = c01; feat[5]  = c02;
    feat[6] = c01; feat[7] = c11; feat[8]  = c12;
    feat[9] = c02; feat[10] = c12; feat[11] = c22;
    float dv = dinv[p];
    unsigned int* hp = (unsigned int*)(hs1 + (size_t)p * 64);
    for (int c = 0; c < 64; c += 2) {
        float a0 = Bl[c], a1 = Bl[c + 1];
        #pragma unroll
        for (int i = 0; i < 12; i++) {
            a0 = fmaf(feat[i], Wl[i * 64 + c], a0);
            a1 = fmaf(feat[i], Wl[i * 64 + c + 1], a1);
        }
        unsigned int pk = (unsigned int)f2bf(dv * selu_f(a0)) |
                          ((unsigned int)f2bf(dv * selu_f(a1)) << 16);
        hp[c >> 1] = pk;
    }
}

// ---------------------------------------------------------------------------
// Fused GCN1: per block, aggregate 128 nodes (C=64) straight into the MFMA
// LDS A-buffer, then gemm vs Wp1 (K=64, N=128) and write bf16 hs2
// (dinv-prescaled).  Single column tile -> no gather replication.
// ---------------------------------------------------------------------------
__global__ __launch_bounds__(256) void gcn1_kernel(
    const unsigned short* __restrict__ hs1, const float* __restrict__ dinv,
    const int* __restrict__ indptr, const int* __restrict__ ssrc,
    const unsigned short* __restrict__ Wp, const float* __restrict__ bias,
    unsigned short* __restrict__ hs2) {
    constexpr int LDA = 72;  // 64 + 8 bf16 pad
    __shared__ unsigned short As[128 * LDA];
    int t = threadIdx.x;
    int R0 = blockIdx.x * 128;
    const uint4* hp = (const uint4*)hs1;

    // aggregation phase: 128 nodes x 8 uint4-chunks = 1024 tasks
    for (int idx = t; idx < 1024; idx += 256) {
        int nl = idx >> 3, cq = idx & 7;
        int node = R0 + nl;
        float a[8];
        {
            uint4 u = hp[(size_t)node * 8 + cq];
            a[0] = bflo(u.x); a[1] = bfhi(u.x);
            a[2] = bflo(u.y); a[3] = bfhi(u.y);
            a[4] = bflo(u.z); a[5] = bfhi(u.z);
            a[6] = bflo(u.w); a[7] = bfhi(u.w);
        }
        int beg = indptr[node], end = indptr[node + 1];
        for (int j = beg; j < end; j += 8) {
            int s[8];
            #pragma unroll
            for (int q = 0; q < 8; q++) s[q] = ssrc[j + q];
            uint4 v[8];
            #pragma unroll
            for (int q = 0; q < 8; q++) v[q] = hp[(size_t)s[q] * 8 + cq];
            #pragma unroll
            for (int q = 0; q < 8; q++) acc8(a, v[q]);
        }
        *(uint4*)&As[nl * LDA + cq * 8] = pack8(a, dinv[node]);
    }
    __syncthreads();

    // gemm phase: K=64 (KS=2), N=128, epilogue dinv*selu -> bf16 hs2
    int wave = t >> 6, l = t & 63;
    int ml = l & 15, q = l >> 4;
    int wr = wave * 32;
    f32x4 acc[2][8];
    #pragma unroll
    for (int mf = 0; mf < 2; mf++)
        #pragma unroll
        for (int nf = 0; nf < 8; nf++) acc[mf][nf] = (f32x4){0.f, 0.f, 0.f, 0.f};
    const bf16x8* wp8 = (const bf16x8*)Wp;
    #pragma unroll
    for (int ks = 0; ks < 2; ks++) {
        bf16x8 af[2];
        #pragma unroll
        for (int mf = 0; mf < 2; mf++)
            af[mf] = *(const bf16x8*)&As[(wr + mf * 16 + ml) * LDA + ks * 32 + q * 8];
        bf16x8 bfr[8];
        #pragma unroll
        for (int nf = 0; nf < 8; nf++)
            bfr[nf] = wp8[(size_t)(nf * 2 + ks) * 64 + l];
        #pragma unroll
        for (int mf = 0; mf < 2; mf++)
            #pragma unroll
            for (int nf = 0; nf < 8; nf++)
                acc[mf][nf] = __builtin_amdgcn_mfma_f32_16x16x32_bf16(
                    af[mf], bfr[nf], acc[mf][nf], 0, 0, 0);
    }
    float bj[8];
    #pragma unroll
    for (int nf = 0; nf < 8; nf++) bj[nf] = bias[nf * 16 + ml];
    #pragma unroll
    for (int mf = 0; mf < 2; mf++) {
        #pragma unroll
        for (int r = 0; r < 4; r++) {
            int row = R0 + wr + mf * 16 + q * 4 + r;
            float dv = dinv[row];
            #pragma unroll
            for (int nf = 0; nf < 8; nf++) {
                float v = dv * selu_f(acc[mf][nf][r] + bj[nf]);
                hs2[(size_t)row * 128 + nf * 16 + ml] = f2bf(v);
            }
        }
    }
}

// ---------------------------------------------------------------------------
// Aggregation (C=128): out[d] = dinv[d]*(hs[d] + sum hs[s]), 8ch/thread,
// 8-deep gather batching over pad-8 CSR.
// ---------------------------------------------------------------------------
__global__ __launch_bounds__(256) void agg128_kernel(
    const unsigned short* __restrict__ hs, const float* __restrict__ dinv,
    const int* __restrict__ indptr, const int* __restrict__ ssrc,
    unsigned short* __restrict__ out, int n_nodes) {
    constexpr int TPN = 16;
    int node = blockIdx.x * (256 / TPN) + threadIdx.x / TPN;
    int cq = threadIdx.x % TPN;
    if (node >= n_nodes) return;
    const uint4* hp = (const uint4*)hs;
    float a[8];
    {
        uint4 u = hp[(size_t)node * TPN + cq];
        a[0] = bflo(u.x); a[1] = bfhi(u.x);
        a[2] = bflo(u.y); a[3] = bfhi(u.y);
        a[4] = bflo(u.z); a[5] = bfhi(u.z);
        a[6] = bflo(u.w); a[7] = bfhi(u.w);
    }
    int beg = indptr[node], end = indptr[node + 1];
    for (int j = beg; j < end; j += 8) {
        int s[8];
        #pragma unroll
        for (int q = 0; q < 8; q++) s[q] = ssrc[j + q];
        uint4 v[8];
        #pragma unroll
        for (int q = 0; q < 8; q++) v[q] = hp[(size_t)s[q] * TPN + cq];
        #pragma unroll
        for (int q = 0; q < 8; q++) acc8(a, v[q]);
    }
    ((uint4*)out)[(size_t)node * TPN + cq] = pack8(a, dinv[node]);
}

// ---------------------------------------------------------------------------
// MFMA bf16 GEMM (K=128): selu + per-tile column max -> pmax
// ---------------------------------------------------------------------------
__global__ __launch_bounds__(256) void gemm2_kernel(
    const unsigned short* __restrict__ A, const unsigned short* __restrict__ Wp,
    const float* __restrict__ bias, float* __restrict__ pmax, int Nfull) {
    constexpr int KS = 4;
    constexpr int LDA = 136;  // 128 + 8
    constexpr int CPR = 16;
    __shared__ unsigned short As[128 * LDA];
    int t = threadIdx.x;
    int wave = t >> 6, l = t & 63;
    int ml = l & 15, q = l >> 4;
    int R0 = blockIdx.x * 128;
    int cb = blockIdx.y * 128;

    for (int c = t; c < 128 * CPR; c += 256) {
        int row = c / CPR, off = c % CPR;
        *(uint4*)&As[row * LDA + off * 8] =
            *(const uint4*)&A[(size_t)(R0 + row) * 128 + off * 8];
    }
    __syncthreads();

    f32x4 acc[2][8];
    #pragma unroll
    for (int mf = 0; mf < 2; mf++)
        #pragma unroll
        for (int nf = 0; nf < 8; nf++) acc[mf][nf] = (f32x4){0.f, 0.f, 0.f, 0.f};

    const bf16x8* wp8 = (const bf16x8*)Wp;
    int wr = wave * 32;
    #pragma unroll
    for (int ks = 0; ks < KS; ks++) {
        bf16x8 af[2];
        #pragma unroll
        for (int mf = 0; mf < 2; mf++)
            af[mf] = *(const bf16x8*)&As[(wr + mf * 16 + ml) * LDA + ks * 32 + q * 8];
        bf16x8 bfr[8];
        #pragma unroll
        for (int nf = 0; nf < 8; nf++)
            bfr[nf] = wp8[(size_t)(((cb >> 4) + nf) * KS + ks) * 64 + l];
        #pragma unroll
        for (int mf = 0; mf < 2; mf++)
            #pragma unroll
            for (int nf = 0; nf < 8; nf++)
                acc[mf][nf] = __builtin_amdgcn_mfma_f32_16x16x32_bf16(
                    af[mf], bfr[nf], acc[mf][nf], 0, 0, 0);
    }

    // selu + column max; C/D layout: col = ml, row = q*4 + r
    float cmax[8];
    #pragma unroll
    for (int nf = 0; nf < 8; nf++) {
        float bj = bias[cb + nf * 16 + ml];
        float v = -INFINITY;
        #pragma unroll
        for (int mf = 0; mf < 2; mf++)
            #pragma unroll
            for (int r = 0; r < 4; r++)
                v = fmaxf(v, selu_f(acc[mf][nf][r] + bj));
        v = fmaxf(v, __shfl_xor(v, 16, 64));
        v = fmaxf(v, __shfl_xor(v, 32, 64));
        cmax[nf] = v;
    }
    __syncthreads();  // before reusing As as f32 scratch
    float* redf = (float*)As;  // [4 waves][128 cols]
    if (ml == l) {  // lanes 0..15
        #pragma unroll
        for (int nf = 0; nf < 8; nf++) redf[wave * 128 + nf * 16 + l] = cmax[nf];
    }
    __syncthreads();
    if (t < 128) {
        float v = redf[t];
        v = fmaxf(v, redf[128 + t]);
        v = fmaxf(v, redf[256 + t]);
        v = fmaxf(v, redf[384 + t]);
        pmax[(size_t)blockIdx.x * Nfull + cb + t] = v;
    }
}

// ---------------------------------------------------------------------------
// lat: m[b][c] = max over 32 pmax tiles; lat = selu(m @ w_e2 + b_e2);
// latw1 = lat @ w_d1[:512] + b_d1; latw2 = lat @ w_d2[:512] + b_d2.
// ---------------------------------------------------------------------------
__global__ __launch_bounds__(256) void lat_kernel(
    const float* __restrict__ pmax, const float* __restrict__ w_e2,
    const float* __restrict__ b_e2, const float* __restrict__ w_d1,
    const float* __restrict__ b_d1, const float* __restrict__ w_d2,
    const float* __restrict__ b_d2, float* __restrict__ latw1,
    float* __restrict__ latw2) {
    int b = blockIdx.x;
    int t = threadIdx.x;
    __shared__ float ml[512], ll[512];
    __shared__ float red[6][256];
    for (int c = t; c < 512; c += 256) {
        const float* p = pmax + (size_t)(b * 32) * 512 + c;
        float v = -INFINITY;
        #pragma unroll
        for (int k = 0; k < 32; k++) v = fmaxf(v, p[k * 512]);
        ml[c] = v;
    }
    __syncthreads();
    for (int cc = 0; cc < 2; cc++) {
        int c = t + cc * 256;
        float acc = b_e2[c];
        for (int k = 0; k < 512; k++) acc = fmaf(ml[k], w_e2[k * 512 + c], acc);
        ll[c] = selu_f(acc);
    }
    __syncthreads();
    float p[6] = {0.f, 0.f, 0.f, 0.f, 0.f, 0.f};
    for (int k = t; k < 512; k += 256) {
        float lv = ll[k];
        #pragma unroll
        for (int j = 0; j < 3; j++) {
            p[j]     = fmaf(lv, w_d1[k * 3 + j], p[j]);
            p[3 + j] = fmaf(lv, w_d2[k * 3 + j], p[3 + j]);
        }
    }
    #pragma unroll
    for (int j = 0; j < 6; j++) red[j][t] = p[j];
    __syncthreads();
    for (int s = 128; s > 0; s >>= 1) {
        if (t < s) {
            #pragma unroll
            for (int j = 0; j < 6; j++) red[j][t] += red[j][t + s];
        }
        __syncthreads();
    }
    if (t < 3) {
        latw1[b * 3 + t] = red[t][0] + b_d1[t];
        latw2[b * 3 + t] = red[3 + t][0] + b_d2[t];
    }
}

// ---------------------------------------------------------------------------
// decoder: per point, grid coords + two 3-wide folds
// ---------------------------------------------------------------------------
__global__ void decode_kernel(const float* __restrict__ latw1, const float* __restrict__ latw2,
                              const float* __restrict__ w_d1, const float* __restrict__ w_d2,
                              float* __restrict__ out, int total) {
    int p = blockIdx.x * blockDim.x + threadIdx.x;
    if (p >= total) return;
    int b = p >> 12;
    int n = p & 4095;
    int i = n / 46;
    int j = n - i * 46;
    float y0 = fmaf((float)i, 119.f / 90.f, 1.f);
    float y1 = fmaf((float)j, 59.f / 45.f, 1.f);
    float k0 = selu_f(latw1[b * 3 + 0] + y0 * w_d1[1536 + 0] + y1 * w_d1[1539 + 0]);
    float k1 = selu_f(latw1[b * 3 + 1] + y0 * w_d1[1536 + 1] + y1 * w_d1[1539 + 1]);
    float k2 = selu_f(latw1[b * 3 + 2] + y0 * w_d1[1536 + 2] + y1 * w_d1[1539 + 2]);
    float o0 = selu_f(latw2[b * 3 + 0] + k0 * w_d2[1536 + 0] + k1 * w_d2[1539 + 0] + k2 * w_d2[1542 + 0]);
    float o1 = selu_f(latw2[b * 3 + 1] + k0 * w_d2[1536 + 1] + k1 * w_d2[1539 + 1] + k2 * w_d2[1542 + 1]);
    float o2 = selu_f(latw2[b * 3 + 2] + k0 * w_d2[1536 + 2] + k1 * w_d2[1539 + 2] + k2 * w_d2[1542 + 2]);
    out[(size_t)p * 3 + 0] = o0;
    out[(size_t)p * 3 + 1] = o1;
    out[(size_t)p * 3 + 2] = o2;
}

// ---------------------------------------------------------------------------
extern "C" void kernel_launch(void* const* d_in, const int* in_sizes, int n_in,
                              void* d_out, int out_size, void* d_ws, size_t ws_size,
                              hipStream_t stream) {
    const float* x    = (const float*)d_in[0];
    const int*   knn  = (const int*)d_in[1];
    const float* w_e1 = (const float*)d_in[2];
    const float* b_e1 = (const float*)d_in[3];
    const float* w_g1 = (const float*)d_in[4];
    const float* b_g1 = (const float*)d_in[5];
    const float* w_g2 = (const float*)d_in[6];
    const float* b_g2 = (const float*)d_in[7];
    const float* w_e2 = (const float*)d_in[8];
    const float* b_e2 = (const float*)d_in[9];
    const float* w_d1 = (const float*)d_in[10];
    const float* b_d1 = (const float*)d_in[11];
    const float* w_d2 = (const float*)d_in[12];
    const float* b_d2 = (const float*)d_in[13];
    float* out = (float*)d_out;

    const int BN = in_sizes[0] / 3;   // 32768
    const int E  = in_sizes[1] / 2;   // 524288
    const int Bb = BN / 4096;         // 8
    const int* src = knn;
    const int* dst = knn + E;

    size_t off = 0;
    auto alloc = [&](size_t bytes) -> void* {
        void* p = (char*)d_ws + off;
        off += (bytes + 255) & ~(size_t)255;
        return p;
    };
    unsigned short* hs1 = (unsigned short*)alloc((size_t)(BN + 1) * 64 * 2);
    unsigned short* hs2 = (unsigned short*)alloc((size_t)(BN + 1) * 128 * 2);
    unsigned short* a2  = (unsigned short*)alloc((size_t)BN * 128 * 2);
    unsigned short* Wp1 = (unsigned short*)alloc((size_t)16 * 64 * 8 * 2);
    unsigned short* Wp2 = (unsigned short*)alloc((size_t)128 * 64 * 8 * 2);
    float* pmax   = (float*)alloc((size_t)(BN / 128) * 512 * 4);
    float* latw1  = (float*)alloc((size_t)Bb * 3 * 4);
    float* latw2  = (float*)alloc((size_t)Bb * 3 * 4);
    float* dinv   = (float*)alloc((size_t)BN * 4);
    int*   cnt    = (int*)alloc((size_t)BN * 4);
    int*   epos   = (int*)alloc((size_t)E * 4);
    int*   indptr = (int*)alloc((size_t)(BN + 1) * 4);
    int*   bsums  = (int*)alloc((size_t)128 * 4);
    int*   ssrc   = (int*)alloc((size_t)(E + 7 * BN + 1024) * 4);
    (void)ws_size;

    // prep: zero cnt + sentinel rows, pack both weight matrices
    prep_kernel<<<273, 256, 0, stream>>>(
        cnt, (unsigned int*)(hs1 + (size_t)BN * 64),
        (unsigned int*)(hs2 + (size_t)BN * 128), w_g1, Wp1, w_g2, Wp2);
    // count + per-edge slot
    count_kernel<<<(E + 255) / 256, 256, 0, stream>>>(dst, cnt, epos, E);
    scanA_kernel<<<BN / 256, 256, 0, stream>>>(cnt, bsums);
    scanC_kernel<<<BN / 256, 256, 0, stream>>>(cnt, bsums, indptr, dinv, ssrc, BN);
    // atomic-free scatter
    scatter_kernel<<<(E + 255) / 256, 256, 0, stream>>>(src, dst, epos, indptr, ssrc, E);

    // encoder (writes dinv-prescaled bf16 hs1)
    cov_enc_kernel<<<(BN + 255) / 256, 256, 0, stream>>>(x, w_e1, b_e1, dinv, hs1, BN);

    // GCN1 fused: agg(64) -> MFMA K=64 -> bf16 hs2 (dinv-prescaled)
    gcn1_kernel<<<BN / 128, 256, 0, stream>>>(hs1, dinv, indptr, ssrc, Wp1, b_g1, hs2);

    // GCN2: agg(128) -> MFMA K=128 + selu + fused column-max
    agg128_kernel<<<BN / 16, 256, 0, stream>>>(hs2, dinv, indptr, ssrc, a2, BN);
    gemm2_kernel<<<dim3(BN / 128, 4), 256, 0, stream>>>(a2, Wp2, b_g2, pmax, 512);

    // max-pool + latent + per-batch decoder coefficients (fused)
    lat_kernel<<<Bb, 256, 0, stream>>>(pmax, w_e2, b_e2, w_d1, b_d1, w_d2, b_d2, latw1, latw2);

    // decoder
    decode_kernel<<<(BN + 255) / 256, 256, 0, stream>>>(latw1, latw2, w_d1, w_d2, out, BN);
}